// Round 1
// baseline (3272.620 us; speedup 1.0000x reference)
//
#include <hip/hip_runtime.h>
#include <hip/hip_bf16.h>
#include <cstdint>
#include <cstddef>

// Problem constants
#define BB 16
#define TT 8192
#define DD 512
#define NHEAD 8
#define NKV 2
#define HD 64
#define KVD 128          // NKV*HD
#define SCALE 0.125f     // 1/sqrt(64)

// Attention tiling
#define NCHUNK 32
#define TCHUNK 256       // TT/NCHUNK
#define TC 32            // rows per register tile
#define LDP 260          // padded LDS row (float4-aligned, bank-conflict-free)

// Workspace float offsets (total 589824 floats = 2.36 MB)
#define WS_Q      0            // BB*512
#define WS_OPART  8192         // BB*NCHUNK*8*64 = 262144
#define WS_ML     270336       // BB*NCHUNK*8*2  = 8192
#define WS_H      278528       // BB*1024        = 16384
#define WS_APART  294912       // 8*BB*2048      = 262144
#define WS_ACT    557056       // BB*2048        = 32768

// ---------------- K1: q projection: q = query @ Wq  [16,512] ----------------
__global__ __launch_bounds__(512) void k_qproj(const float* __restrict__ query,
                                               const float* __restrict__ Wq,
                                               float* __restrict__ wsq) {
    __shared__ float qrow[DD];
    const int b = blockIdx.x, t = threadIdx.x;
    qrow[t] = query[b * DD + t];
    __syncthreads();
    float acc = 0.f;
#pragma unroll 8
    for (int d = 0; d < DD; ++d) acc = fmaf(qrow[d], Wq[d * DD + t], acc);
    wsq[b * DD + t] = acc;
}

// ------- K2: fused K/V projection + flash-decode attention (partials) -------
// Grid (NCHUNK, BB), 256 threads. Thread roles:
//   proj phase : thread = output col c (c<128: K col, else V col), 32-row tile
//   score phase: thread = (head h = tid>>5, row r = tid&31)
//   accum phase: thread = (head h, d2 = tid&31) owning o[h][d2], o[h][d2+32]
__global__ __launch_bounds__(256, 2) void k_attn(const float* __restrict__ enc,
                                                 const float* __restrict__ Wk,
                                                 const float* __restrict__ Wv,
                                                 const float* __restrict__ wsq,
                                                 float* __restrict__ o_part,
                                                 float* __restrict__ ml) {
    __shared__ float kv[TC][LDP];       // cols 0..127 = K, 128..255 = V
    __shared__ float sc[NHEAD * TC];
    __shared__ float qs[DD];

    const int tid = threadIdx.x;
    const int chunk = blockIdx.x, b = blockIdx.y;

    // stage scaled q
    for (int i = tid; i < DD; i += 256) qs[i] = wsq[b * DD + i] * SCALE;

    const int c = tid;
    const float* Wcol = (c < KVD) ? (Wk + c) : (Wv + (c - KVD));
    const int h = tid >> 5, d2 = tid & 31, kvh = h >> 2;

    float m_h = -1e30f, l_h = 0.f, o0 = 0.f, o1 = 0.f;
    const float* encb = enc + ((size_t)b * TT + (size_t)chunk * TCHUNK) * DD;

    for (int tile = 0; tile < TCHUNK / TC; ++tile) {
        // ---- phase A: project 32 rows for this thread's column ----
        float acc[TC];
#pragma unroll
        for (int r = 0; r < TC; ++r) acc[r] = 0.f;
        const float* encT = encb + (size_t)tile * TC * DD;
        for (int k0 = 0; k0 < DD; k0 += 16) {
            float w[16];
#pragma unroll
            for (int kk = 0; kk < 16; ++kk) w[kk] = Wcol[(k0 + kk) * KVD];
#pragma unroll
            for (int r = 0; r < TC; ++r) {
                const float* er = encT + r * DD + k0;   // block-uniform -> s_load
#pragma unroll
                for (int kk = 0; kk < 16; ++kk) acc[r] = fmaf(er[kk], w[kk], acc[r]);
            }
        }
        __syncthreads();                 // prev phase C done; qs staged (tile 0)
#pragma unroll
        for (int r = 0; r < TC; ++r) kv[r][c] = acc[r];
        __syncthreads();

        // ---- phase B: scores s[h][r] = (q_h . k_r) * SCALE ----
        {
            const int rb = tid & 31;
            const float4* kr = (const float4*)(&kv[rb][kvh * HD]);
            const float4* qh = (const float4*)(&qs[h * HD]);
            float s = 0.f;
#pragma unroll
            for (int j = 0; j < HD / 4; ++j) {
                float4 k4 = kr[j], q4 = qh[j];
                s = fmaf(k4.x, q4.x, s); s = fmaf(k4.y, q4.y, s);
                s = fmaf(k4.z, q4.z, s); s = fmaf(k4.w, q4.w, s);
            }
            sc[h * TC + rb] = s;
        }
        __syncthreads();

        // ---- phase C: online softmax update + context accumulation ----
        {
            float mloc = -1e30f;
#pragma unroll
            for (int r = 0; r < TC; ++r) mloc = fmaxf(mloc, sc[h * TC + r]);
            float mnew = fmaxf(m_h, mloc);
            float resc = __expf(m_h - mnew);
            o0 *= resc; o1 *= resc; l_h *= resc;
#pragma unroll
            for (int r = 0; r < TC; ++r) {
                float p = __expf(sc[h * TC + r] - mnew);
                l_h += p;
                o0 = fmaf(p, kv[r][KVD + kvh * HD + d2], o0);
                o1 = fmaf(p, kv[r][KVD + kvh * HD + d2 + 32], o1);
            }
            m_h = mnew;
        }
    }

    const size_t obase = (((size_t)b * NCHUNK + chunk) * NHEAD + h) * HD;
    o_part[obase + d2] = o0;
    o_part[obase + d2 + 32] = o1;
    if (d2 == 0) {
        const size_t mb = (((size_t)b * NCHUNK + chunk) * NHEAD + h) * 2;
        ml[mb] = m_h; ml[mb + 1] = l_h;
    }
}

// -------- K3: combine chunk partials -> context, build h = [ctx|query] ------
__global__ __launch_bounds__(512) void k_reduce(const float* __restrict__ o_part,
                                                const float* __restrict__ ml,
                                                const float* __restrict__ query,
                                                float* __restrict__ hvec) {
    const int b = blockIdx.x, t = threadIdx.x;
    const int h = t >> 6, d = t & 63;
    float M = -1e30f, L = 0.f, O = 0.f;
    for (int i = 0; i < NCHUNK; ++i) {
        const size_t base = ((size_t)b * NCHUNK + i) * NHEAD + h;
        const float mi = ml[base * 2], li = ml[base * 2 + 1];
        const float oi = o_part[base * HD + d];
        const float Mn = fmaxf(M, mi);
        const float f1 = __expf(M - Mn), f2 = __expf(mi - Mn);
        L = L * f1 + li * f2;
        O = O * f1 + oi * f2;
        M = Mn;
    }
    hvec[b * 1024 + h * HD + d] = O / L;
    hvec[b * 1024 + 512 + t] = query[b * DD + t];
}

// ---------------- K4: MLP1 partial GEMM h @ W1 (i-split, no atomics) --------
__global__ __launch_bounds__(256) void k_mlp1(const float* __restrict__ hvec,
                                              const float* __restrict__ W1,
                                              float* __restrict__ apart) {
    const int jb = blockIdx.x, ib = blockIdx.y;
    const int j = jb * 256 + threadIdx.x;
    float acc[BB];
#pragma unroll
    for (int b = 0; b < BB; ++b) acc[b] = 0.f;
    for (int i0 = ib * 128; i0 < ib * 128 + 128; i0 += 4) {
        const float w0 = W1[(size_t)(i0 + 0) * 2048 + j];
        const float w1 = W1[(size_t)(i0 + 1) * 2048 + j];
        const float w2 = W1[(size_t)(i0 + 2) * 2048 + j];
        const float w3 = W1[(size_t)(i0 + 3) * 2048 + j];
#pragma unroll
        for (int b = 0; b < BB; ++b) {
            const float* hb = hvec + b * 1024 + i0;     // uniform -> s_load
            acc[b] = fmaf(hb[0], w0, acc[b]);
            acc[b] = fmaf(hb[1], w1, acc[b]);
            acc[b] = fmaf(hb[2], w2, acc[b]);
            acc[b] = fmaf(hb[3], w3, acc[b]);
        }
    }
#pragma unroll
    for (int b = 0; b < BB; ++b)
        apart[((size_t)ib * BB + b) * 2048 + j] = acc[b];
}

// ---------------- K4b: sum i-partials + SiLU --------------------------------
__global__ __launch_bounds__(256) void k_silu(const float* __restrict__ apart,
                                              float* __restrict__ act) {
    const int idx = blockIdx.x * 256 + threadIdx.x;     // 32768
    float s = 0.f;
#pragma unroll
    for (int ib = 0; ib < 8; ++ib) s += apart[(size_t)ib * BB * 2048 + idx];
    act[idx] = s / (1.f + __expf(-s));
}

// ---------------- K5: MLP2 act @ W2 -> out ----------------------------------
__global__ __launch_bounds__(256) void k_mlp2(const float* __restrict__ act,
                                              const float* __restrict__ W2,
                                              float* __restrict__ out) {
    const int b = blockIdx.y;
    const int d = blockIdx.x * 256 + threadIdx.x;
    const float* ab = act + b * 2048;                   // uniform -> s_load
    float acc = 0.f;
    for (int j0 = 0; j0 < 2048; j0 += 4) {
        acc = fmaf(ab[j0 + 0], W2[(size_t)(j0 + 0) * 512 + d], acc);
        acc = fmaf(ab[j0 + 1], W2[(size_t)(j0 + 1) * 512 + d], acc);
        acc = fmaf(ab[j0 + 2], W2[(size_t)(j0 + 2) * 512 + d], acc);
        acc = fmaf(ab[j0 + 3], W2[(size_t)(j0 + 3) * 512 + d], acc);
    }
    out[b * DD + d] = acc;
}

extern "C" void kernel_launch(void* const* d_in, const int* in_sizes, int n_in,
                              void* d_out, int out_size, void* d_ws, size_t ws_size,
                              hipStream_t stream) {
    const float* query = (const float*)d_in[0];
    const float* enc   = (const float*)d_in[1];
    const float* Wq    = (const float*)d_in[2];
    const float* Wk    = (const float*)d_in[3];
    const float* Wv    = (const float*)d_in[4];
    const float* W1    = (const float*)d_in[5];
    const float* W2    = (const float*)d_in[6];
    float* ws  = (float*)d_ws;
    float* out = (float*)d_out;

    k_qproj<<<dim3(BB), dim3(512), 0, stream>>>(query, Wq, ws + WS_Q);
    k_attn<<<dim3(NCHUNK, BB), dim3(256), 0, stream>>>(enc, Wk, Wv,
                                                       ws + WS_Q, ws + WS_OPART, ws + WS_ML);
    k_reduce<<<dim3(BB), dim3(512), 0, stream>>>(ws + WS_OPART, ws + WS_ML, query, ws + WS_H);
    k_mlp1<<<dim3(8, 8), dim3(256), 0, stream>>>(ws + WS_H, W1, ws + WS_APART);
    k_silu<<<dim3(128), dim3(256), 0, stream>>>(ws + WS_APART, ws + WS_ACT);
    k_mlp2<<<dim3(2, BB), dim3(256), 0, stream>>>(ws + WS_ACT, W2, out);
}

// Round 2
// 246.533 us; speedup vs baseline: 13.2746x; 13.2746x over previous
//
#include <hip/hip_runtime.h>
#include <hip/hip_bf16.h>
#include <cstdint>
#include <cstddef>

#define BB 16
#define TT 8192
#define DD 512
#define NHEAD 8
#define NKV 2
#define HD 64
#define KVD 128
#define SCALE 0.125f

#define MCH 128              // enc rows per attn block
#define NCHUNK (TT / MCH)    // 64
#define BK 64
#define NSTEP (DD / BK)      // 8

typedef __attribute__((ext_vector_type(8))) short bf16x8;
typedef __attribute__((ext_vector_type(4))) float f32x4;

// workspace float offsets
#define WS_Q      0                    // 16*512            = 8192
#define WS_WBT    8192                 // 256*512 u16       = 65536 floats
#define WS_OPART  73728                // 16*64*8*64        = 524288
#define WS_ML     598016               // 16*64*8*2         = 16384
#define WS_H      614400               // 16*1024           = 16384
#define WS_APART  630784               // 16*16*2048        = 524288
#define WS_ACT    1155072              // 16*2048           = 32768
// total 1187840 floats = 4.75 MB

__device__ __forceinline__ ushort f2bf(float f) {
    uint u = __builtin_bit_cast(uint, f);
    u += 0x7fffu + ((u >> 16) & 1u);
    return (ushort)(u >> 16);
}
__device__ __forceinline__ float bf1(ushort s) {
    return __builtin_bit_cast(float, (uint)s << 16);
}
__device__ __forceinline__ float bflo(uint u) {
    return __builtin_bit_cast(float, u << 16);
}
__device__ __forceinline__ float bfhi(uint u) {
    return __builtin_bit_cast(float, u & 0xffff0000u);
}
__device__ __forceinline__ void gload_lds16(const void* g, void* l) {
    __builtin_amdgcn_global_load_lds((const __attribute__((address_space(1))) uint32_t*)g,
                                     (__attribute__((address_space(3))) uint32_t*)l, 16, 0, 0);
}

// ---------------- K0: weights -> bf16, transposed [col][k], pre-swizzled ----
// stored element: wbt[col*512 + (k & ~63) + ((k&63) ^ ((col&7)<<3))] = bf16(Wcat[k][col])
__global__ __launch_bounds__(128) void k_prep_w(const float* __restrict__ Wk,
                                                const float* __restrict__ Wv,
                                                ushort* __restrict__ wbt) {
    const int col = blockIdx.x;          // 0..255
    const int t = threadIdx.x;           // 0..127
    const float* W = (col < KVD) ? (Wk + col) : (Wv + (col - KVD));
#pragma unroll
    for (int kk = 0; kk < 4; ++kk) {
        const int k = t * 4 + kk;
        const float v = W[(size_t)k * KVD];
        const int e = (k & ~63) + ((k & 63) ^ ((col & 7) << 3));
        wbt[(size_t)col * 512 + e] = f2bf(v);
    }
}

// ---------------- K1: q projection (fp32, tiny) -----------------------------
__global__ __launch_bounds__(512) void k_qproj(const float* __restrict__ query,
                                               const float* __restrict__ Wq,
                                               float* __restrict__ wsq) {
    __shared__ float qrow[DD];
    const int b = blockIdx.x, t = threadIdx.x;
    qrow[t] = query[b * DD + t];
    __syncthreads();
    float acc = 0.f;
#pragma unroll 8
    for (int d = 0; d < DD; ++d) acc = fmaf(qrow[d], Wq[d * DD + t], acc);
    wsq[b * DD + t] = acc;
}

// ------- K2: MFMA K/V projection + flash-decode attention (partials) --------
// grid (NCHUNK, BB), 512 threads = 8 waves (2 wm x 4 wn), wave tile 64x64
__global__ __launch_bounds__(512, 1) void k_attn(const float* __restrict__ enc,
                                                 const ushort* __restrict__ wbt,
                                                 const float* __restrict__ wsq,
                                                 float* __restrict__ o_part,
                                                 float* __restrict__ ml) {
    __shared__ __align__(16) char smem[96 * 1024];   // A0|A1 (16K each), B0|B1 (32K each)
    __shared__ float sc[NHEAD * MCH];                // 8*128 scores
    __shared__ float qs[DD];

    const int tid = threadIdx.x;
    const int chunk = blockIdx.x, b = blockIdx.y;
    const int lane = tid & 63, w = tid >> 6;
    const int wm = w >> 2, wn = w & 3;

    qs[tid] = wsq[b * DD + tid] * SCALE;

    const float* encb = enc + ((size_t)b * TT + (size_t)chunk * MCH) * DD;

    char* const A0 = smem;
    char* const A1 = smem + 16 * 1024;
    char* const B0 = smem + 32 * 1024;
    char* const B1 = smem + 64 * 1024;

    const int ar = tid >> 4;             // staging row 0..31 (+p*32)
    const int akq = (tid & 15) * 4;      // staging k offset 0..60

    f32x4 acc[4][4];
#pragma unroll
    for (int i = 0; i < 4; ++i)
#pragma unroll
        for (int j = 0; j < 4; ++j) acc[i][j] = (f32x4){0.f, 0.f, 0.f, 0.f};

    float4 e[4];

    // ---- staging lambdas (plain code, unrolled) ----
#define LOAD_ENC(sstep)                                                              \
    {                                                                                \
        _Pragma("unroll") for (int p = 0; p < 4; ++p)                                \
            e[p] = *(const float4*)(encb + (size_t)(ar + p * 32) * DD +              \
                                    (sstep) * BK + akq);                             \
    }
#define WRITE_A(Abuf)                                                                \
    {                                                                                \
        _Pragma("unroll") for (int p = 0; p < 4; ++p) {                              \
            const int row = ar + p * 32;                                             \
            uint2 u;                                                                 \
            u.x = ((uint)f2bf(e[p].y) << 16) | f2bf(e[p].x);                         \
            u.y = ((uint)f2bf(e[p].w) << 16) | f2bf(e[p].z);                         \
            *(uint2*)((Abuf) + row * 128 + ((akq * 2) ^ ((row & 7) << 4))) = u;      \
        }                                                                            \
    }
#define GLL_B(Bbuf, sstep)                                                           \
    {                                                                                \
        _Pragma("unroll") for (int j = 0; j < 4; ++j) {                              \
            const int col = w * 32 + j * 8 + (lane >> 3);                            \
            const ushort* gsrc = wbt + (size_t)col * 512 + (sstep) * 64 +            \
                                 (lane & 7) * 8;                                     \
            gload_lds16(gsrc, (Bbuf) + (w * 32 + j * 8) * 128);                      \
        }                                                                            \
    }

    // prologue: stage step 0, prefetch enc for step 1
    LOAD_ENC(0);
    GLL_B(B0, 0);
    WRITE_A(A0);
    LOAD_ENC(1);

    for (int s = 0; s < NSTEP; ++s) {
        const int cur = s & 1;
        char* const Ac = cur ? A1 : A0;
        char* const Bc = cur ? B1 : B0;
        char* const An = cur ? A0 : A1;
        char* const Bn = cur ? B0 : B1;
        __syncthreads();
        if (s + 1 < NSTEP) {
            GLL_B(Bn, s + 1);
            WRITE_A(An);                  // e holds step s+1 data
            if (s + 2 < NSTEP) LOAD_ENC(s + 2);
        }
        // compute on cur
#pragma unroll
        for (int kk = 0; kk < 2; ++kk) {
            const int kbyte = kk * 64 + (lane >> 4) * 16;
            bf16x8 af[4], bfr[4];
#pragma unroll
            for (int rt = 0; rt < 4; ++rt) {
                const int row = wm * 64 + rt * 16 + (lane & 15);
                af[rt] = *(const bf16x8*)(Ac + row * 128 + (kbyte ^ ((row & 7) << 4)));
            }
#pragma unroll
            for (int nt = 0; nt < 4; ++nt) {
                const int col = wn * 64 + nt * 16 + (lane & 15);
                bfr[nt] = *(const bf16x8*)(Bc + col * 128 + (kbyte ^ ((col & 7) << 4)));
            }
#pragma unroll
            for (int rt = 0; rt < 4; ++rt)
#pragma unroll
                for (int nt = 0; nt < 4; ++nt)
                    acc[rt][nt] = __builtin_amdgcn_mfma_f32_16x16x32_bf16(
                        af[rt], bfr[nt], acc[rt][nt], 0, 0, 0);
        }
    }

    // ---- epilogue: acc -> bf16 KV tile in LDS (padded stride 258 u16) ----
    __syncthreads();
    ushort* kvl = (ushort*)smem;         // [128][258] bf16 = 66048 B (aliases A/B bufs)
#pragma unroll
    for (int rt = 0; rt < 4; ++rt)
#pragma unroll
        for (int nt = 0; nt < 4; ++nt)
#pragma unroll
            for (int j = 0; j < 4; ++j) {
                const int row = wm * 64 + rt * 16 + (lane >> 4) * 4 + j;
                const int col = wn * 64 + nt * 16 + (lane & 15);
                kvl[row * 258 + col] = f2bf(acc[rt][nt][j]);
            }
    __syncthreads();

    // ---- scores: wave w == head h; lanes cover rows ----
    {
        const int h = w, kvh = h >> 2;
        const float* qh = qs + h * HD;
#pragma unroll
        for (int rr = 0; rr < 2; ++rr) {
            const int r = lane + rr * 64;
            const uint* kr = (const uint*)(kvl + r * 258 + kvh * HD);
            float s = 0.f;
#pragma unroll
            for (int d2 = 0; d2 < 32; ++d2) {
                const uint u = kr[d2];
                s = fmaf(bflo(u), qh[2 * d2], s);
                s = fmaf(bfhi(u), qh[2 * d2 + 1], s);
            }
            sc[h * MCH + r] = s;
        }
    }
    __syncthreads();

    // ---- softmax + PV: thread (h=w, d=lane) ----
    {
        const int h = w, kvh = h >> 2, d = lane;
        float m = -1e30f;
#pragma unroll 8
        for (int r = 0; r < MCH; ++r) m = fmaxf(m, sc[h * MCH + r]);
        float l = 0.f, o = 0.f;
        const ushort* vcol = kvl + KVD + kvh * HD + d;
#pragma unroll 4
        for (int r = 0; r < MCH; ++r) {
            const float p = __expf(sc[h * MCH + r] - m);
            l += p;
            o = fmaf(p, bf1(vcol[r * 258]), o);
        }
        const size_t base = ((size_t)b * NCHUNK + chunk) * NHEAD + h;
        o_part[base * HD + d] = o;
        if (d == 0) { ml[base * 2] = m; ml[base * 2 + 1] = l; }
    }
#undef LOAD_ENC
#undef WRITE_A
#undef GLL_B
}

// -------- K3: combine chunk partials -> context, build h = [ctx|query] ------
__global__ __launch_bounds__(512) void k_reduce(const float* __restrict__ o_part,
                                                const float* __restrict__ ml,
                                                const float* __restrict__ query,
                                                float* __restrict__ hvec) {
    const int b = blockIdx.x, t = threadIdx.x;
    const int h = t >> 6, d = t & 63;
    float M = -1e30f, L = 0.f, O = 0.f;
    for (int i = 0; i < NCHUNK; ++i) {
        const size_t base = ((size_t)b * NCHUNK + i) * NHEAD + h;
        const float mi = ml[base * 2], li = ml[base * 2 + 1];
        const float oi = o_part[base * HD + d];
        const float Mn = fmaxf(M, mi);
        const float f1 = __expf(M - Mn), f2 = __expf(mi - Mn);
        L = L * f1 + li * f2;
        O = O * f1 + oi * f2;
        M = Mn;
    }
    hvec[b * 1024 + h * HD + d] = O / L;
    hvec[b * 1024 + 512 + t] = query[b * DD + t];
}

// ---------------- K4: MLP1 partial GEMM h @ W1 (16-way i-split) -------------
__global__ __launch_bounds__(256) void k_mlp1(const float* __restrict__ hvec,
                                              const float* __restrict__ W1,
                                              float* __restrict__ apart) {
    const int jb = blockIdx.x, ib = blockIdx.y;
    const int j = jb * 256 + threadIdx.x;
    float acc[BB];
#pragma unroll
    for (int b = 0; b < BB; ++b) acc[b] = 0.f;
    for (int i0 = ib * 64; i0 < ib * 64 + 64; i0 += 4) {
        const float w0 = W1[(size_t)(i0 + 0) * 2048 + j];
        const float w1 = W1[(size_t)(i0 + 1) * 2048 + j];
        const float w2 = W1[(size_t)(i0 + 2) * 2048 + j];
        const float w3 = W1[(size_t)(i0 + 3) * 2048 + j];
#pragma unroll
        for (int b = 0; b < BB; ++b) {
            const float* hb = hvec + b * 1024 + i0;
            acc[b] = fmaf(hb[0], w0, acc[b]);
            acc[b] = fmaf(hb[1], w1, acc[b]);
            acc[b] = fmaf(hb[2], w2, acc[b]);
            acc[b] = fmaf(hb[3], w3, acc[b]);
        }
    }
#pragma unroll
    for (int b = 0; b < BB; ++b)
        apart[((size_t)ib * BB + b) * 2048 + j] = acc[b];
}

// ---------------- K4b: sum i-partials + SiLU --------------------------------
__global__ __launch_bounds__(256) void k_silu(const float* __restrict__ apart,
                                              float* __restrict__ act) {
    const int idx = blockIdx.x * 256 + threadIdx.x;
    float s = 0.f;
#pragma unroll
    for (int ib = 0; ib < 16; ++ib) s += apart[(size_t)ib * BB * 2048 + idx];
    act[idx] = s / (1.f + __expf(-s));
}

// ---------------- K5: MLP2 act @ W2 -> out ----------------------------------
__global__ __launch_bounds__(256) void k_mlp2(const float* __restrict__ act,
                                              const float* __restrict__ W2,
                                              float* __restrict__ out) {
    const int b = blockIdx.y;
    const int d = blockIdx.x * 256 + threadIdx.x;
    const float* ab = act + b * 2048;
    float acc = 0.f;
    for (int j0 = 0; j0 < 2048; j0 += 4) {
        acc = fmaf(ab[j0 + 0], W2[(size_t)(j0 + 0) * 512 + d], acc);
        acc = fmaf(ab[j0 + 1], W2[(size_t)(j0 + 1) * 512 + d], acc);
        acc = fmaf(ab[j0 + 2], W2[(size_t)(j0 + 2) * 512 + d], acc);
        acc = fmaf(ab[j0 + 3], W2[(size_t)(j0 + 3) * 512 + d], acc);
    }
    out[b * DD + d] = acc;
}

extern "C" void kernel_launch(void* const* d_in, const int* in_sizes, int n_in,
                              void* d_out, int out_size, void* d_ws, size_t ws_size,
                              hipStream_t stream) {
    const float* query = (const float*)d_in[0];
    const float* enc   = (const float*)d_in[1];
    const float* Wq    = (const float*)d_in[2];
    const float* Wk    = (const float*)d_in[3];
    const float* Wv    = (const float*)d_in[4];
    const float* W1    = (const float*)d_in[5];
    const float* W2    = (const float*)d_in[6];
    float* ws  = (float*)d_ws;
    float* out = (float*)d_out;
    ushort* wbt = (ushort*)(ws + WS_WBT);

    k_prep_w<<<dim3(256), dim3(128), 0, stream>>>(Wk, Wv, wbt);
    k_qproj<<<dim3(BB), dim3(512), 0, stream>>>(query, Wq, ws + WS_Q);
    k_attn<<<dim3(NCHUNK, BB), dim3(512), 0, stream>>>(enc, wbt, ws + WS_Q,
                                                       ws + WS_OPART, ws + WS_ML);
    k_reduce<<<dim3(BB), dim3(512), 0, stream>>>(ws + WS_OPART, ws + WS_ML, query, ws + WS_H);
    k_mlp1<<<dim3(8, 16), dim3(256), 0, stream>>>(ws + WS_H, W1, ws + WS_APART);
    k_silu<<<dim3(128), dim3(256), 0, stream>>>(ws + WS_APART, ws + WS_ACT);
    k_mlp2<<<dim3(2, BB), dim3(256), 0, stream>>>(ws + WS_ACT, W2, out);
}